// Round 2
// baseline (33.339 us; speedup 1.0000x reference)
//
#include <hip/hip_runtime.h>
#include <cstdint>
#include <cstddef>

// Problem constants (from reference)
#define NAGT 256
#define TT   100
#define NPTS (NAGT * TT)   // 25600
#define PU   10
#define PV   20
#define NS   (PU * PV)     // 200
#define MH   2048
#define MW   2048
#define NMAPS 4
#define WORDS_PER_ROW (MW / 32)                     // 64
#define WORDS_PER_MAP (MH * WORDS_PER_ROW)          // 131072
#define TOTAL_F4 (NMAPS * MH * MW / 4)              // 4,194,304 float4 groups

// numpy-style linspace(-0.5, 0.5, n): computed in f64 as i*step - 0.5,
// endpoint forced exactly to 0.5, then cast to f32.
__device__ __forceinline__ float lin_u(int i) {
    if (i == PU - 1) return 0.5f;
    return (float)((double)i * (1.0 / 9.0) - 0.5);
}
__device__ __forceinline__ float lin_v(int i) {
    if (i == PV - 1) return 0.5f;
    return (float)((double)i * (1.0 / 19.0) - 0.5);
}

// ---------------------------------------------------------------------------
// Pass 1: compress float raster (0.0/1.0) -> collision bitmask (bit=1 if <0.5)
// Each lane loads one float4 (4 px) -> 4-bit nibble; 8 lanes' nibbles are
// packed into one uint32 via shfl butterflies; lanes with (lane&7)==0 store.
// Grid chosen so TOTAL_F4 is covered exactly with no bounds checks.
// ---------------------------------------------------------------------------
__global__ __launch_bounds__(256) void compress_kernel(
    const float* __restrict__ raster,
    uint32_t*    __restrict__ bits)
{
    const int tid    = blockIdx.x * blockDim.x + threadIdx.x;
    const int lane   = threadIdx.x & 63;
    const int stride = gridDim.x * blockDim.x;   // 1,048,576

    for (int g = tid; g < TOTAL_F4; g += stride) {   // exactly 4 iterations
        const float4 v = reinterpret_cast<const float4*>(raster)[g];
        uint32_t n = (v.x < 0.5f ? 1u : 0u)
                   | (v.y < 0.5f ? 2u : 0u)
                   | (v.z < 0.5f ? 4u : 0u)
                   | (v.w < 0.5f ? 8u : 0u);
        // pack 8 consecutive lanes' nibbles into 32 bits (valid on lane&7==0)
        n |= (uint32_t)__shfl_xor((int)n, 1, 64) << 4;
        n |= (uint32_t)__shfl_xor((int)n, 2, 64) << 8;
        n |= (uint32_t)__shfl_xor((int)n, 4, 64) << 16;
        if ((lane & 7) == 0) {
            bits[g >> 3] = n;   // word w covers px [32w, 32w+32)
        }
    }
}

// ---------------------------------------------------------------------------
// Pass 2: per-point footprint test against the bitmask (one wave per point).
// Identical math / reduce / tie-break to the verified round-1 kernel.
// ---------------------------------------------------------------------------
__global__ __launch_bounds__(256) void envcoll_bits_kernel(
    const float*    __restrict__ traj,     // [NPTS,4]
    const float*    __restrict__ veh_att,  // [NAGT,2]
    const uint32_t* __restrict__ bits,     // [NMAPS][MH][MW/32]
    const int*      __restrict__ mapixes,  // [NAGT]
    const float*    __restrict__ dxp,      // [1]
    float*          __restrict__ out)      // [NPTS]
{
    const int gtid = blockIdx.x * blockDim.x + threadIdx.x;
    const int wid  = gtid >> 6;         // one wave per trajectory point
    const int lane = threadIdx.x & 63;
    if (wid >= NPTS) return;

    const int a = wid / TT;

    const float cx = traj[wid * 4 + 0];
    const float cy = traj[wid * 4 + 1];
    const float h0 = traj[wid * 4 + 2];
    const float h1 = traj[wid * 4 + 3];
    const float Lv = veh_att[a * 2 + 0];
    const float Wv = veh_att[a * 2 + 1];
    const int   mp = mapixes[a];
    const float dxv = dxp[0];

    // h / (||h|| + 1e-8), exact reference op order
    const float nrm = __fsqrt_rn(__fadd_rn(__fmul_rn(h0, h0), __fmul_rn(h1, h1)));
    const float den = __fadd_rn(nrm, 1e-8f);
    const float h0n = __fdiv_rn(h0, den);
    const float h1n = __fdiv_rn(h1, den);

    const uint32_t* __restrict__ bb = bits + (size_t)mp * WORDS_PER_MAP;

    unsigned long long best = ~0ULL;   // key = (d2_bits << 32) | k

    #pragma unroll
    for (int it = 0; it < 4; ++it) {
        const int k = lane + it * 64;
        if (k < NS) {
            const int iu = k / PV;
            const int iv = k - iu * PV;
            const float uf = lin_u(iu);
            const float vf = lin_v(iv);
            const float bu = __fmul_rn(uf, Lv);
            const float bv = __fmul_rn(vf, Wv);
            const float ox = __fsub_rn(__fmul_rn(bu, h0n), __fmul_rn(bv, h1n));
            const float oy = __fadd_rn(__fmul_rn(bu, h1n), __fmul_rn(bv, h0n));
            const float px = __fadd_rn(cx, ox);
            const float py = __fadd_rn(cy, oy);
            int ix = (int)floorf(__fdiv_rn(px, dxv));
            int iy = (int)floorf(__fdiv_rn(py, dxv));
            ix = min(max(ix, 0), MW - 1);
            iy = min(max(iy, 0), MH - 1);
            const uint32_t w = bb[iy * WORDS_PER_ROW + (ix >> 5)];
            if ((w >> (ix & 31)) & 1u) {   // collision (val < 0.5)
                const float d2 = __fadd_rn(__fmul_rn(ox, ox), __fmul_rn(oy, oy));
                const unsigned long long key =
                    ((unsigned long long)__float_as_uint(d2) << 32) | (unsigned int)k;
                best = (key < best) ? key : best;
            }
        }
    }

    #pragma unroll
    for (int off = 32; off > 0; off >>= 1) {
        const unsigned long long o = __shfl_xor(best, off, 64);
        best = (o < best) ? o : best;
    }

    if (lane == 0) {
        float result = 0.0f;
        if (best != ~0ULL) {
            const int k = (int)(best & 0xffffffffu);
            const int iu = k / PV;
            const int iv = k - iu * PV;
            const float uf = lin_u(iu);
            const float vf = lin_v(iv);
            const float bu = __fmul_rn(uf, Lv);
            const float bv = __fmul_rn(vf, Wv);
            const float ox = __fsub_rn(__fmul_rn(bu, h0n), __fmul_rn(bv, h1n));
            const float oy = __fadd_rn(__fmul_rn(bu, h1n), __fmul_rn(bv, h0n));
            const float px = __fadd_rn(cx, ox);   // = coll point x
            const float py = __fadd_rn(cy, oy);
            const float ddx = __fsub_rn(cx, px);  // diff = ctr - cp (reference)
            const float ddy = __fsub_rn(cy, py);
            const float dist = __fsqrt_rn(__fadd_rn(__fmul_rn(ddx, ddx),
                                                    __fmul_rn(ddy, ddy)));
            const float pl  = __fdiv_rn(__fmul_rn(Lv, Lv), 4.0f);
            const float pw  = __fdiv_rn(__fmul_rn(Wv, Wv), 4.0f);
            const float pen = __fsqrt_rn(__fadd_rn(pl, pw));
            result = __fsub_rn(1.0f, __fdiv_rn(dist, pen));
        }
        out[wid] = result;
    }
}

// ---------------------------------------------------------------------------
// Fallback (direct float raster reads) — only used if ws_size is too small.
// Identical to the verified round-1 kernel.
// ---------------------------------------------------------------------------
__global__ __launch_bounds__(256) void envcoll_direct_kernel(
    const float* __restrict__ traj,
    const float* __restrict__ veh_att,
    const float* __restrict__ raster,
    const int*   __restrict__ mapixes,
    const float* __restrict__ dxp,
    float*       __restrict__ out)
{
    const int gtid = blockIdx.x * blockDim.x + threadIdx.x;
    const int wid  = gtid >> 6;
    const int lane = threadIdx.x & 63;
    if (wid >= NPTS) return;

    const int a = wid / TT;
    const float cx = traj[wid * 4 + 0];
    const float cy = traj[wid * 4 + 1];
    const float h0 = traj[wid * 4 + 2];
    const float h1 = traj[wid * 4 + 3];
    const float Lv = veh_att[a * 2 + 0];
    const float Wv = veh_att[a * 2 + 1];
    const int   mp = mapixes[a];
    const float dxv = dxp[0];

    const float nrm = __fsqrt_rn(__fadd_rn(__fmul_rn(h0, h0), __fmul_rn(h1, h1)));
    const float den = __fadd_rn(nrm, 1e-8f);
    const float h0n = __fdiv_rn(h0, den);
    const float h1n = __fdiv_rn(h1, den);

    const float* __restrict__ rb = raster + (size_t)mp * ((size_t)MH * MW);
    unsigned long long best = ~0ULL;

    #pragma unroll
    for (int it = 0; it < 4; ++it) {
        const int k = lane + it * 64;
        if (k < NS) {
            const int iu = k / PV;
            const int iv = k - iu * PV;
            const float uf = lin_u(iu);
            const float vf = lin_v(iv);
            const float bu = __fmul_rn(uf, Lv);
            const float bv = __fmul_rn(vf, Wv);
            const float ox = __fsub_rn(__fmul_rn(bu, h0n), __fmul_rn(bv, h1n));
            const float oy = __fadd_rn(__fmul_rn(bu, h1n), __fmul_rn(bv, h0n));
            const float px = __fadd_rn(cx, ox);
            const float py = __fadd_rn(cy, oy);
            int ix = (int)floorf(__fdiv_rn(px, dxv));
            int iy = (int)floorf(__fdiv_rn(py, dxv));
            ix = min(max(ix, 0), MW - 1);
            iy = min(max(iy, 0), MH - 1);
            const float val = rb[(size_t)iy * MW + ix];
            if (val < 0.5f) {
                const float d2 = __fadd_rn(__fmul_rn(ox, ox), __fmul_rn(oy, oy));
                const unsigned long long key =
                    ((unsigned long long)__float_as_uint(d2) << 32) | (unsigned int)k;
                best = (key < best) ? key : best;
            }
        }
    }
    #pragma unroll
    for (int off = 32; off > 0; off >>= 1) {
        const unsigned long long o = __shfl_xor(best, off, 64);
        best = (o < best) ? o : best;
    }
    if (lane == 0) {
        float result = 0.0f;
        if (best != ~0ULL) {
            const int k = (int)(best & 0xffffffffu);
            const int iu = k / PV;
            const int iv = k - iu * PV;
            const float uf = lin_u(iu);
            const float vf = lin_v(iv);
            const float bu = __fmul_rn(uf, Lv);
            const float bv = __fmul_rn(vf, Wv);
            const float ox = __fsub_rn(__fmul_rn(bu, h0n), __fmul_rn(bv, h1n));
            const float oy = __fadd_rn(__fmul_rn(bu, h1n), __fmul_rn(bv, h0n));
            const float px = __fadd_rn(cx, ox);
            const float py = __fadd_rn(cy, oy);
            const float ddx = __fsub_rn(cx, px);
            const float ddy = __fsub_rn(cy, py);
            const float dist = __fsqrt_rn(__fadd_rn(__fmul_rn(ddx, ddx),
                                                    __fmul_rn(ddy, ddy)));
            const float pl  = __fdiv_rn(__fmul_rn(Lv, Lv), 4.0f);
            const float pw  = __fdiv_rn(__fmul_rn(Wv, Wv), 4.0f);
            const float pen = __fsqrt_rn(__fadd_rn(pl, pw));
            result = __fsub_rn(1.0f, __fdiv_rn(dist, pen));
        }
        out[wid] = result;
    }
}

extern "C" void kernel_launch(void* const* d_in, const int* in_sizes, int n_in,
                              void* d_out, int out_size, void* d_ws, size_t ws_size,
                              hipStream_t stream) {
    const float* traj    = (const float*)d_in[0];
    const float* veh_att = (const float*)d_in[1];
    const float* raster  = (const float*)d_in[2];
    const int*   mapixes = (const int*)d_in[3];
    const float* dxp     = (const float*)d_in[4];
    float* out = (float*)d_out;

    const size_t bits_bytes = (size_t)NMAPS * WORDS_PER_MAP * sizeof(uint32_t); // 2 MiB

    const int block = 256;
    const int grid_main = (NPTS * 64 + block - 1) / block;   // 6400

    if (ws_size >= bits_bytes) {
        uint32_t* bits = (uint32_t*)d_ws;
        // Pass 1: 4096 blocks x 256 thr; stride 1,048,576 covers 4,194,304 f4
        hipLaunchKernelGGL(compress_kernel, dim3(4096), dim3(block), 0, stream,
                           raster, bits);
        // Pass 2
        hipLaunchKernelGGL(envcoll_bits_kernel, dim3(grid_main), dim3(block), 0,
                           stream, traj, veh_att, bits, mapixes, dxp, out);
    } else {
        hipLaunchKernelGGL(envcoll_direct_kernel, dim3(grid_main), dim3(block), 0,
                           stream, traj, veh_att, raster, mapixes, dxp, out);
    }
}

// Round 3
// 21.572 us; speedup vs baseline: 1.5454x; 1.5454x over previous
//
#include <hip/hip_runtime.h>
#include <cstdint>
#include <cstddef>

// Problem constants (from reference)
#define NAGT 256
#define TT   100
#define NPTS (NAGT * TT)   // 25600
#define PU   10
#define PV   20
#define NS   (PU * PV)     // 200
#define MH   2048
#define MW   2048

// Compile-time linspace tables, bit-identical to the verified round-1 formula:
// (float)((double)i * (1.0/9.0 or 1.0/19.0) - 0.5), endpoint forced to 0.5f.
#define LUE(i, invn) ((float)((double)(i) * (invn) - 0.5))
__device__ __constant__ float LUT_U[PU] = {
    LUE(0, 1.0/9.0), LUE(1, 1.0/9.0), LUE(2, 1.0/9.0), LUE(3, 1.0/9.0),
    LUE(4, 1.0/9.0), LUE(5, 1.0/9.0), LUE(6, 1.0/9.0), LUE(7, 1.0/9.0),
    LUE(8, 1.0/9.0), 0.5f
};
__device__ __constant__ float LUT_V[PV] = {
    LUE(0,  1.0/19.0), LUE(1,  1.0/19.0), LUE(2,  1.0/19.0), LUE(3,  1.0/19.0),
    LUE(4,  1.0/19.0), LUE(5,  1.0/19.0), LUE(6,  1.0/19.0), LUE(7,  1.0/19.0),
    LUE(8,  1.0/19.0), LUE(9,  1.0/19.0), LUE(10, 1.0/19.0), LUE(11, 1.0/19.0),
    LUE(12, 1.0/19.0), LUE(13, 1.0/19.0), LUE(14, 1.0/19.0), LUE(15, 1.0/19.0),
    LUE(16, 1.0/19.0), LUE(17, 1.0/19.0), LUE(18, 1.0/19.0), 0.5f
};

// Sample geometry, exact reference op order (no contraction).
__device__ __forceinline__ void sample_geom(
    int k, float Lv, float Wv, float h0n, float h1n, float cx, float cy,
    float& ox, float& oy, float& px, float& py)
{
    const int iu = k / PV;
    const int iv = k - iu * PV;
    const float bu = __fmul_rn(LUT_U[iu], Lv);
    const float bv = __fmul_rn(LUT_V[iv], Wv);
    ox = __fsub_rn(__fmul_rn(bu, h0n), __fmul_rn(bv, h1n));
    oy = __fadd_rn(__fmul_rn(bu, h1n), __fmul_rn(bv, h0n));
    px = __fadd_rn(cx, ox);
    py = __fadd_rn(cy, oy);
}

template<bool POW2>
__device__ __forceinline__ void point_body(
    int wid, int lane,
    const float* __restrict__ traj,
    const float* __restrict__ veh_att,
    const float* __restrict__ raster,
    const int*   __restrict__ mapixes,
    float dxv, float inv_dx,
    float* __restrict__ out)
{
    // wave-uniform point index -> scalar loads
    const int ws = __builtin_amdgcn_readfirstlane(wid);
    const int a  = ws / TT;

    const float cx = traj[ws * 4 + 0];
    const float cy = traj[ws * 4 + 1];
    const float h0 = traj[ws * 4 + 2];
    const float h1 = traj[ws * 4 + 3];
    const float Lv = veh_att[a * 2 + 0];
    const float Wv = veh_att[a * 2 + 1];
    const int   mp = mapixes[a];

    // h / (||h|| + 1e-8), exact reference op order
    const float nrm = __fsqrt_rn(__fadd_rn(__fmul_rn(h0, h0), __fmul_rn(h1, h1)));
    const float den = __fadd_rn(nrm, 1e-8f);
    const float h0n = __fdiv_rn(h0, den);
    const float h1n = __fdiv_rn(h1, den);

    const float* __restrict__ rb = raster + (size_t)mp * ((size_t)MH * MW);

    unsigned long long best = ~0ULL;   // key = (d2_bits << 32) | k

    #pragma unroll
    for (int it = 0; it < 4; ++it) {
        const int k = lane + it * 64;
        if (k < NS) {
            float ox, oy, px, py;
            sample_geom(k, Lv, Wv, h0n, h1n, cx, cy, ox, oy, px, py);
            const float qx = POW2 ? __fmul_rn(px, inv_dx) : __fdiv_rn(px, dxv);
            const float qy = POW2 ? __fmul_rn(py, inv_dx) : __fdiv_rn(py, dxv);
            int ix = __float2int_rd(qx);   // == (int)floorf(qx)
            int iy = __float2int_rd(qy);
            ix = min(max(ix, 0), MW - 1);
            iy = min(max(iy, 0), MH - 1);
            const float val = rb[(iy << 11) | ix];
            if (val < 0.5f) {
                const float d2 = __fadd_rn(__fmul_rn(ox, ox), __fmul_rn(oy, oy));
                const unsigned long long key =
                    ((unsigned long long)__float_as_uint(d2) << 32) | (unsigned int)k;
                best = (key < best) ? key : best;
            }
        }
    }

    // wave-wide min reduce (64 lanes)
    #pragma unroll
    for (int off = 32; off > 0; off >>= 1) {
        const unsigned long long o = __shfl_xor(best, off, 64);
        best = (o < best) ? o : best;
    }

    if (lane == 0) {
        float result = 0.0f;
        if (best != ~0ULL) {
            const int k = (int)(best & 0xffffffffu);
            float ox, oy, px, py;
            sample_geom(k, Lv, Wv, h0n, h1n, cx, cy, ox, oy, px, py);
            const float ddx = __fsub_rn(cx, px);  // diff = ctr - cp (reference)
            const float ddy = __fsub_rn(cy, py);
            const float dist = __fsqrt_rn(__fadd_rn(__fmul_rn(ddx, ddx),
                                                    __fmul_rn(ddy, ddy)));
            const float pl  = __fdiv_rn(__fmul_rn(Lv, Lv), 4.0f);
            const float pw  = __fdiv_rn(__fmul_rn(Wv, Wv), 4.0f);
            const float pen = __fsqrt_rn(__fadd_rn(pl, pw));
            result = __fsub_rn(1.0f, __fdiv_rn(dist, pen));
        }
        out[wid] = result;
    }
}

__global__ __launch_bounds__(256) void envcoll_kernel(
    const float* __restrict__ traj,     // [NPTS,4]
    const float* __restrict__ veh_att,  // [NAGT,2]
    const float* __restrict__ raster,   // [4,MH,MW]
    const int*   __restrict__ mapixes,  // [NAGT]
    const float* __restrict__ dxp,      // [1]
    float*       __restrict__ out)      // [NPTS]
{
    const int gtid = blockIdx.x * blockDim.x + threadIdx.x;
    const int wid  = gtid >> 6;
    const int lane = threadIdx.x & 63;
    if (wid >= NPTS) return;

    const float dxv = dxp[0];
    const unsigned int u = __float_as_uint(dxv);
    const unsigned int ex = (u >> 23) & 0xffu;
    const bool pow2 = ((u & 0x007fffffu) == 0u) && ex != 0u && ex != 255u
                      && dxv > 0.0f;
    // exact for pow2 dx: 1/dx and x*(1/dx) are pure exponent shifts
    const float inv_dx = __fdiv_rn(1.0f, dxv);

    if (pow2) {
        point_body<true >(wid, lane, traj, veh_att, raster, mapixes, dxv, inv_dx, out);
    } else {
        point_body<false>(wid, lane, traj, veh_att, raster, mapixes, dxv, inv_dx, out);
    }
}

extern "C" void kernel_launch(void* const* d_in, const int* in_sizes, int n_in,
                              void* d_out, int out_size, void* d_ws, size_t ws_size,
                              hipStream_t stream) {
    const float* traj    = (const float*)d_in[0];
    const float* veh_att = (const float*)d_in[1];
    const float* raster  = (const float*)d_in[2];
    const int*   mapixes = (const int*)d_in[3];
    const float* dxp     = (const float*)d_in[4];
    float* out = (float*)d_out;

    const int block = 256;
    const int grid  = (NPTS * 64) / block;   // 6400
    hipLaunchKernelGGL(envcoll_kernel, dim3(grid), dim3(block), 0, stream,
                       traj, veh_att, raster, mapixes, dxp, out);
}